// Round 1
// 269.450 us; speedup vs baseline: 1.0171x; 1.0171x over previous
//
#include <hip/hip_runtime.h>
#include <stdint.h>

#define TT 2048
#define DD 256
#define KK 1024
#define BB 16
#define NQ (BB*TT)   // 32768 queries per tensor

typedef __attribute__((ext_vector_type(8))) short short8;
typedef __attribute__((ext_vector_type(4))) float f32x4;

#define AS1 __attribute__((address_space(1)))
#define AS3 __attribute__((address_space(3)))

__device__ __forceinline__ short bf16_rn(float x){
  unsigned u = __builtin_bit_cast(unsigned, x);
  unsigned r = u + 0x7fffu + ((u >> 16) & 1u);   // round-to-nearest-even
  return (short)(r >> 16);
}
__device__ __forceinline__ float bf16_to_f(short h){
  unsigned u = ((unsigned)(unsigned short)h) << 16;
  return __builtin_bit_cast(float, u);
}

// ---------------------------------------------------------------------------
// Prep 1: split both codebooks into bf16 hi/lo, swizzled so each (code-tile,
// k-step) block is 64 lanes x 16B contiguous (for global_load_lds width=16).
// layout per tensor: [hi: 1024*256 shorts][lo: 1024*256 shorts]
// pos = ((ct*8 + s)*64 + lane)*8 + j ; lane = q*16 + c ; code = ct*16+c ;
// d = s*32 + q*8 + j
// ---------------------------------------------------------------------------
__global__ void vq_prep_split(const float* __restrict__ cb_top,
                              const float* __restrict__ cb_bot,
                              short* __restrict__ ws_cb){
  int gid = blockIdx.x*256 + threadIdx.x;          // 2*1024*256 = 524288
  int t = gid >> 18;
  int rem = gid & ((1<<18)-1);
  int k = rem >> 8, d = rem & 255;
  const float* cb = t ? cb_bot : cb_top;
  float v = cb[(size_t)k*DD + d];
  short hi = bf16_rn(v);
  short lo = bf16_rn(v - bf16_to_f(hi));
  int ct = k >> 4, c = k & 15, s = d >> 5, rr = d & 31, q = rr >> 3, j = rr & 7;
  int lanei = q*16 + c;
  size_t pos = ((size_t)(ct*8 + s)*64 + lanei)*8 + j;
  short* hib = ws_cb + (size_t)t * (2*KK*DD);
  hib[pos] = hi;
  hib[(size_t)KK*DD + pos] = lo;
}

// ---------------------------------------------------------------------------
// Prep 2: |e_k|^2 in fp32, one wave per code.
// ---------------------------------------------------------------------------
__global__ void vq_prep_e2(const float* __restrict__ cb_top,
                           const float* __restrict__ cb_bot,
                           float* __restrict__ e2_all){
  int gid = blockIdx.x*256 + threadIdx.x;          // 512 blocks -> 2048 waves
  int wv = gid >> 6, lane = gid & 63;
  int t = wv >> 10, k = wv & 1023;
  const float* row = (t ? cb_bot : cb_top) + (size_t)k*DD;
  f32x4 v = *(const f32x4*)(row + lane*4);
  float s = v[0]*v[0] + v[1]*v[1] + v[2]*v[2] + v[3]*v[3];
  #pragma unroll
  for (int off = 1; off < 64; off <<= 1) s += __shfl_xor(s, off, 64);
  if (lane == 0) e2_all[t*KK + k] = s;
}

// ---------------------------------------------------------------------------
// Main fused kernel. grid (256, 2), block 256. Wave: 32 queries; WG: 128.
// Counted-vmcnt pipeline (T3/T4): 4 x 16 KiB ring of 16-code chunks, depth-2
// prefetch, ONE raw s_barrier per chunk, never vmcnt(0) in steady state.
// Ring safety: during window (B(c-1),B(c)) in-flight writes hit bufs
// {c, c+1, c+2} mod 4; the only buffer being read is (c-1) mod 4 — disjoint.
// |e|^2 lives in LDS so the loop's ONLY vmem ops are the counted
// global_load_lds (an in-loop global e2 load would force vmcnt(0) because
// vmcnt retires in order).
// ---------------------------------------------------------------------------
__device__ __forceinline__ void prefetch_ct(const short* cbhi, const short* cblo,
                                            short* smem, int ct, int w, int lane){
  #pragma unroll
  for (int k2 = 0; k2 < 4; ++k2){
    int bi = w*4 + k2;                              // 0..15 block of 1KiB
    int s = bi >> 1, hl = bi & 1;
    const short* src = (hl ? cblo : cbhi) + (size_t)(ct*8 + s)*512 + lane*8;
    short* dst = smem + bi*512 + lane*8;            // lane0 value = uniform base
    __builtin_amdgcn_global_load_lds((AS1 void*)src, (AS3 void*)dst, 16, 0, 0);
  }
}

__global__ __launch_bounds__(256, 2) void vq_main(
    const float* __restrict__ h_top, const float* __restrict__ h_bot,
    const float* __restrict__ cb_top, const float* __restrict__ cb_bot,
    const short* __restrict__ ws_cb, const float* __restrict__ e2_all,
    int* __restrict__ counts, float* __restrict__ loss_acc,
    float* __restrict__ out)
{
  const int tz = blockIdx.y;
  const float* __restrict__ h   = tz ? h_bot : h_top;
  const float* __restrict__ cbf = tz ? cb_bot : cb_top;
  const short* cbhi = ws_cb + (size_t)tz * (2*KK*DD);
  const short* cblo = cbhi + KK*DD;
  const float* e2 = e2_all + tz*KK;
  float* zout = out + (size_t)tz * ((size_t)NQ*DD);

  const int tid = threadIdx.x;
  const int w = tid >> 6, lane = tid & 63;
  const int c16 = lane & 15, q = lane >> 4;
  const int n0 = blockIdx.x*128 + w*32;             // first query of this wave
  const int b = n0 >> 11, t0 = n0 & (TT-1);
  const float* hb = h + (size_t)b * DD * TT;        // h[b][d][t] = hb[d*TT + t]

  __shared__ short smem[4][8192];                   // 4 x 16 KiB ring
  __shared__ float e2s[KK];                         // 4 KiB

  // issue chunks 0 and 1 early: they overlap the long h prologue below
  prefetch_ct(cbhi, cblo, smem[0], 0, w, lane);
  prefetch_ct(cbhi, cblo, smem[1], 1, w, lane);

  // |e|^2 -> LDS (global load + ds_write; drained via lgkmcnt before loop)
  *(f32x4*)(e2s + tid*4) = *(const f32x4*)(e2 + tid*4);

  // ---- prologue: 32 queries x 256 dims -> bf16 hi/lo B-fragments + |x|^2 ----
  short8 bhi[2][8], blo[2][8];
  float x2[2] = {0.f, 0.f};
  #pragma unroll
  for (int g = 0; g < 2; ++g){
    const int tq = t0 + g*16 + c16;
    #pragma unroll
    for (int s = 0; s < 8; ++s){
      #pragma unroll
      for (int j = 0; j < 8; ++j){
        const int d = s*32 + q*8 + j;               // B[k=d][n=c] frag element
        float v = hb[(size_t)d*TT + tq];
        x2[g] += v*v;
        short hi = bf16_rn(v);
        float lo = v - bf16_to_f(hi);
        bhi[g][s][j] = hi;
        blo[g][s][j] = bf16_rn(lo);
      }
    }
  }

  float bestv[2] = {3.4e38f, 3.4e38f};
  int   besti[2] = {0, 0};

  // own e2s ds_writes complete before first barrier (visibility after B(0))
  asm volatile("s_waitcnt lgkmcnt(0)" ::: "memory");

  for (int c = 0; c < 64; ++c){
    if (c < 62){
      prefetch_ct(cbhi, cblo, smem[(c+2)&3], c+2, w, lane);
      // 12 in flight (c,c+1,c+2); wait until 8 remain -> chunk c landed
      asm volatile("s_waitcnt vmcnt(8)" ::: "memory");
    } else if (c == 62){
      asm volatile("s_waitcnt vmcnt(4)" ::: "memory");
    } else {
      asm volatile("s_waitcnt vmcnt(0)" ::: "memory");
    }
    __builtin_amdgcn_s_barrier();                   // raw: no vmcnt(0) drain
    __builtin_amdgcn_sched_barrier(0);              // keep ds_reads below B

    const short* sb = smem[c & 3];
    f32x4 acc0 = {0,0,0,0}, acc1 = {0,0,0,0};
    #pragma unroll
    for (int s = 0; s < 8; ++s){
      short8 ahi = *(const short8*)(sb + (s*2 + 0)*512 + lane*8);
      short8 alo = *(const short8*)(sb + (s*2 + 1)*512 + lane*8);
      acc0 = __builtin_amdgcn_mfma_f32_16x16x32_bf16(ahi, bhi[0][s], acc0, 0,0,0);
      acc1 = __builtin_amdgcn_mfma_f32_16x16x32_bf16(ahi, bhi[1][s], acc1, 0,0,0);
      acc0 = __builtin_amdgcn_mfma_f32_16x16x32_bf16(ahi, blo[0][s], acc0, 0,0,0);
      acc1 = __builtin_amdgcn_mfma_f32_16x16x32_bf16(ahi, blo[1][s], acc1, 0,0,0);
      acc0 = __builtin_amdgcn_mfma_f32_16x16x32_bf16(alo, bhi[0][s], acc0, 0,0,0);
      acc1 = __builtin_amdgcn_mfma_f32_16x16x32_bf16(alo, bhi[1][s], acc1, 0,0,0);
    }
    const int code0 = c*16 + q*4;                   // C row = code, col = query
    const f32x4 e2v = *(const f32x4*)(e2s + code0); // LDS read (lgkmcnt)
    #pragma unroll
    for (int r = 0; r < 4; ++r){
      float s0 = e2v[r] - 2.0f*acc0[r];
      if (s0 < bestv[0]){ bestv[0] = s0; besti[0] = code0 + r; }
      float s1 = e2v[r] - 2.0f*acc1[r];
      if (s1 < bestv[1]){ bestv[1] = s1; besti[1] = code0 + r; }
    }
    // no trailing barrier needed: next writer of buf (c&3) is L(c+4), issued
    // only after all waves passed B(c+1), i.e. after all finished reading it.
  }

  // ---- reduce best/|x|^2 across the 4 quads (codes are quad-partitioned) ----
  #pragma unroll
  for (int off = 16; off <= 32; off <<= 1){
    #pragma unroll
    for (int g = 0; g < 2; ++g){
      float ov = __shfl_xor(bestv[g], off, 64);
      int   oi = __shfl_xor(besti[g], off, 64);
      if (ov < bestv[g] || (ov == bestv[g] && oi < besti[g])){ bestv[g] = ov; besti[g] = oi; }
      x2[g] += __shfl_xor(x2[g], off, 64);
    }
  }

  const int j32 = lane & 31;                        // query within wave
  const int g = (lane >> 4) & 1;                    // (j32>>4) == (lane>>4)&1
  const int myidx = besti[g];

  if (lane < 32) atomicAdd(&counts[tz*KK + myidx], 1);

  // loss: sum of dist = |x|^2 + bestscore, each query counted once
  float ld = (lane < 32) ? (x2[g] + bestv[g]) : 0.0f;
  #pragma unroll
  for (int off = 1; off < 64; off <<= 1) ld += __shfl_xor(ld, off, 64);
  if (lane == 0) atomicAdd(&loss_acc[tz], ld);

  // ---- z_st = codebook[idx] in [B, D, T] layout (fp32 gather, L2-resident) ----
  const int half = lane >> 5;                       // d range 0..127 / 128..255
  const float* crow = cbf + (size_t)myidx * DD + half*128;
  const int tq = t0 + j32;
  float* zb = zout + (size_t)(b*DD + half*128) * TT + tq;
  #pragma unroll 4
  for (int dd = 0; dd < 128; dd += 4){
    f32x4 cv = *(const f32x4*)(crow + dd);
    zb[(size_t)(dd+0)*TT] = cv[0];
    zb[(size_t)(dd+1)*TT] = cv[1];
    zb[(size_t)(dd+2)*TT] = cv[2];
    zb[(size_t)(dd+3)*TT] = cv[3];
  }
}

// ---------------------------------------------------------------------------
// Finalize: perplexities + loss scalars. outs points at d_out + 2*NQ*DD.
// order: vq_loss, commitment_loss, ppl_top, ppl_bot
// ---------------------------------------------------------------------------
__global__ void vq_final(const int* __restrict__ counts,
                         const float* __restrict__ loss_acc,
                         float* __restrict__ outs){
  __shared__ float red[1024];
  const int tid = threadIdx.x;
  for (int t = 0; t < 2; ++t){
    float p = (float)counts[t*KK + tid] * (1.0f/(float)NQ);
    red[tid] = p * logf(p + 1e-10f);
    __syncthreads();
    for (int s = 512; s > 0; s >>= 1){
      if (tid < s) red[tid] += red[tid + s];
      __syncthreads();
    }
    if (tid == 0) outs[2 + t] = expf(-red[0]);
    __syncthreads();
  }
  if (tid == 0){
    float l = (loss_acc[0] + loss_acc[1]) * (1.0f/8388608.0f);  // mean over B*D*T each
    outs[0] = l;   // vq_loss
    outs[1] = l;   // commitment_loss (same forward value)
  }
}

extern "C" void kernel_launch(void* const* d_in, const int* in_sizes, int n_in,
                              void* d_out, int out_size, void* d_ws, size_t ws_size,
                              hipStream_t stream)
{
  (void)in_sizes; (void)n_in; (void)out_size; (void)ws_size;
  const float* h_top  = (const float*)d_in[0];
  const float* h_bot  = (const float*)d_in[1];
  const float* cb_top = (const float*)d_in[2];
  const float* cb_bot = (const float*)d_in[3];
  float* out = (float*)d_out;
  char* ws = (char*)d_ws;

  short* ws_cb    = (short*)ws;                          // 2 MiB (2 tensors x hi/lo)
  float* e2       = (float*)(ws + (2u<<20));             // 8 KiB
  int*   counts   = (int*)  (ws + (2u<<20) + 8192);      // 8 KiB
  float* loss_acc = (float*)(ws + (2u<<20) + 16384);     // 8 B

  hipMemsetAsync(counts, 0, 8192 + 64, stream);          // counts + loss
  vq_prep_split<<<2048, 256, 0, stream>>>(cb_top, cb_bot, ws_cb);
  vq_prep_e2<<<512, 256, 0, stream>>>(cb_top, cb_bot, e2);
  vq_main<<<dim3(256, 2), 256, 0, stream>>>(h_top, h_bot, cb_top, cb_bot,
                                            ws_cb, e2, counts, loss_acc, out);
  vq_final<<<1, 1024, 0, stream>>>(counts, loss_acc, out + (size_t)2*NQ*DD);
}